// Round 2
// baseline (240.886 us; speedup 1.0000x reference)
//
#include <hip/hip_runtime.h>

// Problem constants (match reference)
#define Bsz 32
#define Csz 256
#define Hsz 64
#define Wsz 64
#define BIN 16
#define ROWSTRIDE 68   // 64 + 4 pad: keeps rows 16B-aligned, shifts banks by 4/row

// One block per (b,c) plane pair. Stage the touched row window of both
// feature planes into LDS with coalesced float4 loads, then sample bilinear
// taps from LDS. Thread t -> output (i = t/16, j = t%16); out flat index ==
// blockIdx*256 + t, so stores are fully coalesced.
__global__ __launch_bounds__(256) void roi_feature_kernel(
    const float* __restrict__ orig,
    const float* __restrict__ lab,
    const float* __restrict__ attk,
    float* __restrict__ out)
{
    __shared__ float lds[2][Hsz][ROWSTRIDE];

    const int tid = threadIdx.x;
    const int bc  = blockIdx.x;          // b*256 + c
    const int b   = bc >> 8;

    // lab[b,0,{1,2,3,4}] — broadcast reads
    const float* lb = lab + b * 5;
    const float l1 = lb[1], l2 = lb[2], l3 = lb[3], l4 = lb[4];

    // Closed form of reference coordinate math:
    //   x(j) = 4*l3*(j-8) + 64*l1 - 0.5 ;  y(i) = 4*l4*(i-8) + 64*l2 - 0.5
    const float ya = 4.0f * l4;
    const float yb = 64.0f * l2 - 0.5f;
    const float y_lo = fminf(ya * (0 - 8) + yb, ya * (15 - 8) + yb);
    const float y_hi = fmaxf(ya * (0 - 8) + yb, ya * (15 - 8) + yb);

    int ry0 = (int)floorf(y_lo);
    int ry1 = (int)floorf(y_hi) + 1;
    ry0 = min(max(ry0, 0), Hsz - 1);
    ry1 = min(max(ry1, ry0), Hsz - 1);
    const int nrows = ry1 - ry0 + 1;

    const size_t plane = (size_t)bc * (Hsz * Wsz);
    const float* __restrict__ f0 = orig + plane + ry0 * Wsz;
    const float* __restrict__ f1 = attk + plane + ry0 * Wsz;

    // Stage nrows full rows (64 floats each) for both maps, float4-coalesced.
    const int nvec = nrows * (Wsz / 4);          // <= 64*16 = 1024
    for (int v = tid; v < nvec; v += 256) {
        const int row = v >> 4;
        const int col = (v & 15) * 4;
        const float4 a = *(const float4*)(f0 + row * Wsz + col);
        const float4 c = *(const float4*)(f1 + row * Wsz + col);
        *(float4*)&lds[0][row][col] = a;
        *(float4*)&lds[1][row][col] = c;
    }
    __syncthreads();

    const int j = tid & (BIN - 1);
    const int i = tid >> 4;

    const float x = 4.0f * l3 * (float)(j - 8) + 64.0f * l1 - 0.5f;
    const float y = ya * (float)(i - 8) + yb;

    const float x0f = floorf(x);
    const float y0f = floorf(y);
    const int x0 = (int)x0f;
    const int y0 = (int)y0f;
    const int x1 = x0 + 1;
    const int y1 = y0 + 1;
    const float wx1 = x - x0f, wx0 = 1.0f - wx1;
    const float wy1 = y - y0f, wy0 = 1.0f - wy1;

    float acc0 = 0.0f, acc1 = 0.0f;
#pragma unroll
    for (int k = 0; k < 4; ++k) {
        const int xi = (k & 1) ? x1 : x0;
        const int yi = (k & 2) ? y1 : y0;
        const float w = ((k & 1) ? wx1 : wx0) * ((k & 2) ? wy1 : wy0);
        const bool valid = (xi >= 0) && (xi < Wsz) && (yi >= 0) && (yi < Hsz);
        const float wv = valid ? w : 0.0f;
        const int xc = min(max(xi, 0), Wsz - 1);
        const int yc = min(max(yi, 0), Hsz - 1) - ry0;   // in-window by construction
        acc0 += lds[0][yc][xc] * wv;
        acc1 += lds[1][yc][xc] * wv;
    }

    const int gidx = bc * 256 + tid;
    out[gidx] = acc0;
    out[gidx + Bsz * Csz * BIN * BIN] = acc1;
}

extern "C" void kernel_launch(void* const* d_in, const int* in_sizes, int n_in,
                              void* d_out, int out_size, void* d_ws, size_t ws_size,
                              hipStream_t stream) {
    const float* orig = (const float*)d_in[0];
    const float* lab  = (const float*)d_in[1];
    const float* attk = (const float*)d_in[2];
    float* out = (float*)d_out;

    roi_feature_kernel<<<Bsz * Csz, 256, 0, stream>>>(orig, lab, attk, out);
}

// Round 3
// 235.818 us; speedup vs baseline: 1.0215x; 1.0215x over previous
//
#include <hip/hip_runtime.h>

// Problem constants (match reference)
#define Bsz 32
#define Csz 256
#define Hsz 64
#define Wsz 64
#define BIN 16

// One thread per output element of output_1; computes output_2 too (same
// coordinates/weights, different feature map). tid -> (b,c,i,j), j fastest,
// so stores are fully coalesced (out flat index == tid). The 8 gather loads
// per thread hit a ~17x17 window per (b,c) plane that L1/L2 absorb; total
// distinct HBM footprint ~44 MB << the ~143 MB of full-row staging.
// Nontemporal stores keep the 16.8 MB output stream from evicting input
// windows in L2.
__global__ __launch_bounds__(256) void roi_feature_kernel(
    const float* __restrict__ orig,
    const float* __restrict__ lab,
    const float* __restrict__ attk,
    float* __restrict__ out)
{
    const int tid = blockIdx.x * blockDim.x + threadIdx.x;
    const int j = tid & (BIN - 1);
    const int i = (tid >> 4) & (BIN - 1);
    const int c = (tid >> 8) & (Csz - 1);
    const int b = tid >> 16;

    // lab[b,0,{1,2,3,4}] — broadcast reads, L1-cached
    const float* lb = lab + b * 5;
    const float l1 = lb[1], l2 = lb[2], l3 = lb[3], l4 = lb[4];

    // Closed form of reference coordinate math:
    //   x(j) = 4*l3*(j-8) + 64*l1 - 0.5 ;  y(i) = 4*l4*(i-8) + 64*l2 - 0.5
    const float x = 2.0f * (float)(j - BIN / 2) * l3 / (float)BIN * (float)Wsz
                    + ((l1 * 2.0f - 1.0f + 1.0f) * (float)Wsz - 1.0f) * 0.5f
                    - (2.0f * (float)(j - BIN / 2) * l3 / (float)BIN) * (float)Wsz * 0.5f;
    // NOTE: keep EXACT reference arithmetic order instead of the fused form:
    const float gx = 2.0f * (float)(j - BIN / 2) * l3 / (float)BIN + (l1 * 2.0f - 1.0f);
    const float gy = 2.0f * (float)(i - BIN / 2) * l4 / (float)BIN + (l2 * 2.0f - 1.0f);
    const float xr = ((gx + 1.0f) * (float)Wsz - 1.0f) * 0.5f;
    const float yr = ((gy + 1.0f) * (float)Hsz - 1.0f) * 0.5f;
    (void)x;

    const float x0f = floorf(xr);
    const float y0f = floorf(yr);
    const int x0 = (int)x0f;
    const int y0 = (int)y0f;
    const int x1 = x0 + 1;
    const int y1 = y0 + 1;
    const float wx1 = xr - x0f, wx0 = 1.0f - wx1;
    const float wy1 = yr - y0f, wy0 = 1.0f - wy1;

    const size_t plane = (size_t)(b * Csz + c) * (Hsz * Wsz);
    const float* __restrict__ f0 = orig + plane;
    const float* __restrict__ f1 = attk + plane;

    float acc0 = 0.0f, acc1 = 0.0f;
#pragma unroll
    for (int k = 0; k < 4; ++k) {
        const int xi = (k & 1) ? x1 : x0;
        const int yi = (k & 2) ? y1 : y0;
        const float w = ((k & 1) ? wx1 : wx0) * ((k & 2) ? wy1 : wy0);
        const bool valid = (xi >= 0) && (xi < Wsz) && (yi >= 0) && (yi < Hsz);
        const int xc = min(max(xi, 0), Wsz - 1);
        const int yc = min(max(yi, 0), Hsz - 1);
        const float wv = valid ? w : 0.0f;
        const int off = yc * Wsz + xc;
        acc0 += f0[off] * wv;
        acc1 += f1[off] * wv;
    }

    __builtin_nontemporal_store(acc0, out + tid);
    __builtin_nontemporal_store(acc1, out + tid + (size_t)Bsz * Csz * BIN * BIN);
}

extern "C" void kernel_launch(void* const* d_in, const int* in_sizes, int n_in,
                              void* d_out, int out_size, void* d_ws, size_t ws_size,
                              hipStream_t stream) {
    const float* orig = (const float*)d_in[0];
    const float* lab  = (const float*)d_in[1];
    const float* attk = (const float*)d_in[2];
    float* out = (float*)d_out;

    const int total = Bsz * Csz * BIN * BIN;  // 2,097,152 threads
    roi_feature_kernel<<<total / 256, 256, 0, stream>>>(orig, lab, attk, out);
}